// Round 8
// baseline (589.705 us; speedup 1.0000x reference)
//
#include <hip/hip_runtime.h>
#include <hip/hip_bf16.h>
#include <math.h>

#define BB 2
#define LL 2048
#define DMODEL 1024
#define DINNER 2048
#define DSTATE 16
#define DTRANK 64
#define NROWS (BB * LL)   // 4096
#define NC 64             // number of time chunks
#define CK 32             // chunk length (NC*CK == LL)
#define KS 16             // split-K factor for x_proj
#define KCH (DINNER / KS) // 128

typedef __bf16 bf16x8 __attribute__((ext_vector_type(8)));
typedef float  f32x4  __attribute__((ext_vector_type(4)));
typedef ushort us8    __attribute__((ext_vector_type(8)));
typedef __attribute__((address_space(3))) void       as3_void;
typedef const __attribute__((address_space(1))) void as1_cvoid;

__device__ __forceinline__ ushort f2bf(float x) {
    __hip_bfloat16 h = __float2bfloat16(x);
    return *(ushort*)&h;
}
__device__ __forceinline__ float bf2f(ushort u) {
    unsigned int v = ((unsigned int)u) << 16;
    return *(float*)&v;
}

// ---------------- LayerNorm -> bf16 output ----------------------------------
__global__ __launch_bounds__(256) void ln_kernel(const float* __restrict__ x,
                                                 const float* __restrict__ w,
                                                 const float* __restrict__ b,
                                                 __hip_bfloat16* __restrict__ xn) {
    int row = blockIdx.x;
    const float* xr = x + (size_t)row * DMODEL;
    float4 v = reinterpret_cast<const float4*>(xr)[threadIdx.x];
    float s  = v.x + v.y + v.z + v.w;
    float ss = v.x * v.x + v.y * v.y + v.z * v.z + v.w * v.w;
    for (int off = 32; off > 0; off >>= 1) {
        s  += __shfl_down(s, off);
        ss += __shfl_down(ss, off);
    }
    __shared__ float red0[4], red1[4];
    __shared__ float mu_s, rstd_s;
    int lane = threadIdx.x & 63, wv = threadIdx.x >> 6;
    if (lane == 0) { red0[wv] = s; red1[wv] = ss; }
    __syncthreads();
    if (threadIdx.x == 0) {
        float S = red0[0] + red0[1] + red0[2] + red0[3];
        float SS = red1[0] + red1[1] + red1[2] + red1[3];
        float mu = S * (1.0f / DMODEL);
        float var = SS * (1.0f / DMODEL) - mu * mu;
        mu_s = mu;
        rstd_s = rsqrtf(var + 1e-5f);
    }
    __syncthreads();
    float mu = mu_s, rstd = rstd_s;
    float4 wv4 = reinterpret_cast<const float4*>(w)[threadIdx.x];
    float4 bv4 = reinterpret_cast<const float4*>(b)[threadIdx.x];
    ushort4 o;
    o.x = f2bf((v.x - mu) * rstd * wv4.x + bv4.x);
    o.y = f2bf((v.y - mu) * rstd * wv4.y + bv4.y);
    o.z = f2bf((v.z - mu) * rstd * wv4.z + bv4.z);
    o.w = f2bf((v.w - mu) * rstd * wv4.w + bv4.w);
    *reinterpret_cast<ushort4*>((ushort*)xn + (size_t)row * DMODEL + threadIdx.x * 4) = o;
}

// ---------------- f32 -> bf16 convert (weights) ------------------------------
__global__ __launch_bounds__(256) void cvt_kernel(const float* __restrict__ in,
                                                  __hip_bfloat16* __restrict__ o) {
    int i = (blockIdx.x * 256 + threadIdx.x) * 4;
    float4 v = *reinterpret_cast<const float4*>(in + i);
    ushort4 p;
    p.x = f2bf(v.x); p.y = f2bf(v.y); p.z = f2bf(v.z); p.w = f2bf(v.w);
    *reinterpret_cast<ushort4*>((ushort*)o + i) = p;
}

// ---------------- bf16 MFMA GEMM: C[M,N] = A[M,K] @ W[N,K]^T  ----------------
// EPI 0: bf16 stores, split: n < nsplit -> C; n >= nsplit -> C2 (both ushort*)
// EPI 1: softplus(acc + R[n]) -> bf16 store to C   (R = bias)
// EPI 2: fp32 store with residual: C[m*ldc+n] = acc + R[m*ldc+n]
template <int EPI>
__global__ __launch_bounds__(256) void gemm_bf16(
    const __hip_bfloat16* __restrict__ A, int lda,
    const __hip_bfloat16* __restrict__ W, int ldw,
    void* __restrict__ C, void* __restrict__ C2, int nsplit, int ldc,
    int K, const float* __restrict__ R) {
    __shared__ ushort As[128][32];
    __shared__ ushort Bs[128][32];
    int tid = threadIdx.x;
    int w = tid >> 6, lane = tid & 63;
    int m0 = blockIdx.y * 128, n0 = blockIdx.x * 128;
    int wr = w >> 1, wc = w & 1;

    int srow = (w << 4) + (lane >> 2);
    int skoff = (lane & 3) << 3;
    const ushort* gA = (const ushort*)A + (size_t)(m0 + srow) * lda + skoff;
    const ushort* gB = (const ushort*)W + (size_t)(n0 + srow) * ldw + skoff;
    char* ldsA0 = (char*)&As[0][0] + w * 1024;
    char* ldsB0 = (char*)&Bs[0][0] + w * 1024;

    f32x4 acc[4][4] = {};
    int frow = (lane & 15);
    int fk   = (lane >> 4) << 3;

    for (int k0 = 0; k0 < K; k0 += 32) {
        __syncthreads();
        __builtin_amdgcn_global_load_lds((as1_cvoid*)(gA + k0),                    (as3_void*)(ldsA0),        16, 0, 0);
        __builtin_amdgcn_global_load_lds((as1_cvoid*)(gA + (size_t)64 * lda + k0), (as3_void*)(ldsA0 + 4096), 16, 0, 0);
        __builtin_amdgcn_global_load_lds((as1_cvoid*)(gB + k0),                    (as3_void*)(ldsB0),        16, 0, 0);
        __builtin_amdgcn_global_load_lds((as1_cvoid*)(gB + (size_t)64 * ldw + k0), (as3_void*)(ldsB0 + 4096), 16, 0, 0);
        __syncthreads();

        bf16x8 af[4], bfr[4];
#pragma unroll
        for (int mi = 0; mi < 4; mi++)
            af[mi] = *(const bf16x8*)&As[wr * 64 + mi * 16 + frow][fk];
#pragma unroll
        for (int ni = 0; ni < 4; ni++)
            bfr[ni] = *(const bf16x8*)&Bs[wc * 64 + ni * 16 + frow][fk];
#pragma unroll
        for (int mi = 0; mi < 4; mi++)
#pragma unroll
            for (int ni = 0; ni < 4; ni++)
                acc[mi][ni] = __builtin_amdgcn_mfma_f32_16x16x32_bf16(
                    af[mi], bfr[ni], acc[mi][ni], 0, 0, 0);
    }

    int crow = (lane >> 4) << 2;
    int ccol = lane & 15;
    bool toz = (EPI == 0) && (n0 >= nsplit);
    int nbase = toz ? (n0 - nsplit) : n0;
    ushort* Cu = toz ? (ushort*)C2 : (ushort*)C;
#pragma unroll
    for (int mi = 0; mi < 4; mi++) {
#pragma unroll
        for (int ni = 0; ni < 4; ni++) {
#pragma unroll
            for (int r = 0; r < 4; r++) {
                int m = m0 + wr * 64 + mi * 16 + crow + r;
                int n = nbase + wc * 64 + ni * 16 + ccol;
                float v = acc[mi][ni][r];
                if (EPI == 2) {
                    v += R[(size_t)m * ldc + n];
                    ((float*)C)[(size_t)m * ldc + n] = v;
                } else if (EPI == 1) {
                    v += R[n];
                    v = (v > 20.f) ? v : log1pf(__expf(v));
                    ((ushort*)C)[(size_t)m * ldc + n] = f2bf(v);
                } else {
                    Cu[(size_t)m * ldc + n] = f2bf(v);
                }
            }
        }
    }
}

// ---------------- x_proj split-K (bf16 A): partial + reduce ------------------
__global__ __launch_bounds__(256) void xp_partial(
    const ushort* __restrict__ A,  // u16 [4096][2048] bf16
    const float* __restrict__ W,   // x_proj_w [96][2048]
    float* __restrict__ P) {       // [KS][4096][96]
    __shared__ float As[16][64];
    __shared__ float Ws[16][64];
    int m0 = blockIdx.y * 64;
    int n0 = blockIdx.x * 64;
    int kbase = blockIdx.z * KCH;
    int tid = threadIdx.x;
    int tm = tid >> 4, tn = tid & 15;
    int lr = tid >> 2;
    int lk = (tid & 3) << 2;

    float acc[4][4] = {};

    for (int k0 = kbase; k0 < kbase + KCH; k0 += 16) {
        ushort4 au = *reinterpret_cast<const ushort4*>(A + (size_t)(m0 + lr) * DINNER + k0 + lk);
        float4 av = make_float4(bf2f(au.x), bf2f(au.y), bf2f(au.z), bf2f(au.w));
        float4 wvv;
        int wn = n0 + lr;
        if (wn < 96)
            wvv = *reinterpret_cast<const float4*>(W + (size_t)wn * DINNER + k0 + lk);
        else
            wvv = make_float4(0.f, 0.f, 0.f, 0.f);
        __syncthreads();
        As[lk + 0][lr] = av.x; As[lk + 1][lr] = av.y;
        As[lk + 2][lr] = av.z; As[lk + 3][lr] = av.w;
        Ws[lk + 0][lr] = wvv.x; Ws[lk + 1][lr] = wvv.y;
        Ws[lk + 2][lr] = wvv.z; Ws[lk + 3][lr] = wvv.w;
        __syncthreads();
#pragma unroll
        for (int k = 0; k < 16; k++) {
            float4 a = *reinterpret_cast<const float4*>(&As[k][tm << 2]);
            float4 bv = *reinterpret_cast<const float4*>(&Ws[k][tn << 2]);
            float ar[4] = {a.x, a.y, a.z, a.w};
            float br[4] = {bv.x, bv.y, bv.z, bv.w};
#pragma unroll
            for (int i = 0; i < 4; i++)
#pragma unroll
                for (int j = 0; j < 4; j++)
                    acc[i][j] = fmaf(ar[i], br[j], acc[i][j]);
        }
    }
    float* Pz = P + (size_t)blockIdx.z * NROWS * 96;
#pragma unroll
    for (int i = 0; i < 4; i++) {
        int m = m0 + (tm << 2) + i;
#pragma unroll
        for (int j = 0; j < 4; j++) {
            int n = n0 + (tn << 2) + j;
            if (n < 96)
                Pz[(size_t)m * 96 + n] = acc[i][j];
        }
    }
}

// reduce partials -> xdbl fp32 (scan B/C) + xdbl bf16 (dt MFMA input)
__global__ __launch_bounds__(256) void xp_reduce(
    const float* __restrict__ P, float* __restrict__ xdbl,
    ushort* __restrict__ xdbl16) {
    int i = blockIdx.x * 256 + threadIdx.x;
    float s = 0.f;
#pragma unroll
    for (int z = 0; z < KS; z++)
        s += P[(size_t)z * NROWS * 96 + i];
    xdbl[i] = s;
    xdbl16[i] = f2bf(s);
}

// ------ causal depthwise conv (width 4) + SiLU; bf16 in/out, 8 ch/thread -----
__global__ __launch_bounds__(256) void conv_silu_kernel(
    const ushort* __restrict__ xc16, const float* __restrict__ cw,
    const float* __restrict__ cb, ushort* __restrict__ u16) {
    int r = blockIdx.x;
    int l = r & (LL - 1);
    int c0 = threadIdx.x << 3;            // 8 channels per thread
    const ushort* base = xc16 + (size_t)r * DINNER + c0;
    us8 z8 = {0, 0, 0, 0, 0, 0, 0, 0};
    us8 v0 = *(const us8*)(base);
    us8 v1 = (l >= 1) ? *(const us8*)(base - DINNER)     : z8;
    us8 v2 = (l >= 2) ? *(const us8*)(base - 2 * DINNER) : z8;
    us8 v3 = (l >= 3) ? *(const us8*)(base - 3 * DINNER) : z8;
    us8 o;
#pragma unroll
    for (int j = 0; j < 8; j++) {
        float4 wj = reinterpret_cast<const float4*>(cw)[c0 + j];
        float acc = cb[c0 + j];
        acc = fmaf(bf2f(v3[j]), wj.x, acc);
        acc = fmaf(bf2f(v2[j]), wj.y, acc);
        acc = fmaf(bf2f(v1[j]), wj.z, acc);
        acc = fmaf(bf2f(v0[j]), wj.w, acc);
        float sig = 1.f / (1.f + __expf(-acc));
        o[j] = f2bf(acc * sig);
    }
    *(us8*)(u16 + (size_t)r * DINNER + c0) = o;
}

// --------------- chunked selective scan, s-parallel (16 lanes/channel) -------
// Thread layout per block: 256 threads = 16 channels (dl = tid>>4) x 16 states
// (s = tid&15).  Grid: BB*NC*(DINNER/16) = 16384 blocks.
// hloc/aprod layout: [bc][d][s]  (s fastest -> fully coalesced).
__global__ __launch_bounds__(256) void scan_pass1(
    const ushort* __restrict__ dt16, const ushort* __restrict__ u16,
    const float* __restrict__ xdbl, const float* __restrict__ A_log,
    float* __restrict__ hloc, float* __restrict__ aprod) {
    int gb = blockIdx.x;
    int bc = gb >> 7;                      // b*NC + c
    int b = bc >> 6, c = bc & (NC - 1);
    int dg = gb & 127;                     // channel group
    int tid = threadIdx.x;
    int dl = tid >> 4, s = tid & 15;
    int d = (dg << 4) + dl;

    float a2 = -__expf(A_log[(dg << 8) + tid]) * 1.44269504089f;  // A_log[d*16+s]
    float h = 0.f, ap = 1.f;

    int t0 = c * CK;
    const ushort* dtp = dt16 + ((size_t)b * LL + t0) * DINNER + d;
    const ushort* up  = u16  + ((size_t)b * LL + t0) * DINNER + d;
    const float* xr0  = xdbl + ((size_t)b * LL + t0) * 96 + 64 + s;

    for (int t = 0; t < CK; t++) {
        float dtv = bf2f(dtp[(size_t)t * DINNER]);
        float uv  = bf2f(up[(size_t)t * DINNER]);
        float Bv  = xr0[t * 96];
        float dA  = exp2f(dtv * a2);
        h  = fmaf(dA, h, dtv * uv * Bv);
        ap *= dA;
    }
    size_t off = (((size_t)bc * DINNER + d) << 4) + s;
    hloc[off]  = h;
    aprod[off] = ap;
}

// Pass 2: exclusive scan over chunks per (b,d,s); hloc becomes chunk-initial.
__global__ __launch_bounds__(256) void scan_pass2(
    float* __restrict__ hloc, const float* __restrict__ aprod) {
    int idx = blockIdx.x * 256 + threadIdx.x;   // (b*DINNER + d)*16 + s
    int s = idx & 15;
    int d = (idx >> 4) & (DINNER - 1);
    int b = idx >> 15;
    float run = 0.f;
    for (int c = 0; c < NC; c++) {
        size_t off = ((((size_t)(b * NC + c)) * DINNER + d) << 4) + s;
        float hl = hloc[off];
        float ap = aprod[off];
        hloc[off] = run;
        run = fmaf(ap, run, hl);
    }
}

__global__ __launch_bounds__(256) void scan_pass3(
    const ushort* __restrict__ dt16, const ushort* __restrict__ u16,
    const float* __restrict__ xdbl, const ushort* __restrict__ zb,
    const float* __restrict__ A_log, const float* __restrict__ Dp,
    const float* __restrict__ hinit, __hip_bfloat16* __restrict__ y) {
    int gb = blockIdx.x;
    int bc = gb >> 7;
    int b = bc >> 6, c = bc & (NC - 1);
    int dg = gb & 127;
    int tid = threadIdx.x;
    int dl = tid >> 4, s = tid & 15;
    int d = (dg << 4) + dl;

    float a2 = -__expf(A_log[(dg << 8) + tid]) * 1.44269504089f;
    float Dd = Dp[d];
    float h = hinit[(((size_t)bc * DINNER + d) << 4) + s];

    int t0 = c * CK;
    const ushort* dtp = dt16 + ((size_t)b * LL + t0) * DINNER + d;
    const ushort* up  = u16  + ((size_t)b * LL + t0) * DINNER + d;
    const ushort* zp  = zb   + ((size_t)b * LL + t0) * DINNER + d;
    const float* xr0  = xdbl + ((size_t)b * LL + t0) * 96 + 64 + s;
    ushort* yp = (ushort*)y + ((size_t)b * LL + t0) * DINNER + d;

    for (int t = 0; t < CK; t++) {
        float dtv = bf2f(dtp[(size_t)t * DINNER]);
        float uv  = bf2f(up[(size_t)t * DINNER]);
        float Bv  = xr0[t * 96];
        float Cv  = xr0[t * 96 + 16];
        float dA  = exp2f(dtv * a2);
        h = fmaf(dA, h, dtv * uv * Bv);
        float p = h * Cv;
        p += __shfl_xor(p, 1);
        p += __shfl_xor(p, 2);
        p += __shfl_xor(p, 4);
        p += __shfl_xor(p, 8);
        float zv = bf2f(zp[(size_t)t * DINNER]);
        float sig = 1.f / (1.f + __expf(-zv));
        float yv = (p + uv * Dd) * (zv * sig);
        if (s == 0)
            yp[(size_t)t * DINNER] = f2bf(yv);
    }
}

// ---------------------------------------------------------------------------
extern "C" void kernel_launch(void* const* d_in, const int* in_sizes, int n_in,
                              void* d_out, int out_size, void* d_ws, size_t ws_size,
                              hipStream_t stream) {
    const float* x         = (const float*)d_in[0];
    const float* norm_w    = (const float*)d_in[1];
    const float* norm_b    = (const float*)d_in[2];
    const float* in_proj_w = (const float*)d_in[3];
    const float* conv_w    = (const float*)d_in[4];
    const float* conv_b    = (const float*)d_in[5];
    const float* x_proj_w  = (const float*)d_in[6];
    const float* dt_proj_w = (const float*)d_in[7];
    const float* dt_proj_b = (const float*)d_in[8];
    const float* A_log     = (const float*)d_in[9];
    const float* Dp        = (const float*)d_in[10];
    const float* out_proj_w= (const float*)d_in[11];
    float* out = (float*)d_out;

    float* ws   = (float*)d_ws;
    const size_t NI = (size_t)NROWS * DINNER;          // 8,388,608 elements
    ushort* xc16  = (ushort*)ws;                       // NI bf16
    ushort* zb    = (ushort*)(ws + NI / 2);            // NI bf16
    ushort* u16   = (ushort*)(ws + NI);                // NI bf16
    ushort* dt16  = (ushort*)(ws + NI + NI / 2);       // NI bf16
    float*  xdbl  = ws + 2 * NI;                       // NROWS*96 fp32
    ushort* xdbl16 = (ushort*)(xdbl + (size_t)NROWS * 96);   // NROWS*96 bf16
    float*  nxt   = xdbl + (size_t)NROWS * 96 + (size_t)NROWS * 96 / 2;
    __hip_bfloat16* xnb = (__hip_bfloat16*)nxt;        // NROWS*DMODEL bf16
    __hip_bfloat16* ybb = xnb + (size_t)NROWS * DMODEL;
    __hip_bfloat16* wib = ybb + NI;                    // in_proj_w bf16
    __hip_bfloat16* wob = wib + (size_t)2 * DINNER * DMODEL;
    __hip_bfloat16* wdt = wob + (size_t)DMODEL * DINNER;     // dt_proj_w bf16
    float* hloc  = (float*)(wdt + (size_t)DINNER * DTRANK);  // NI/2 fp32
    float* aprod = hloc + NI / 2;                            // NI/2 fp32
    float* xpp   = aprod + NI / 2;                           // KS*NROWS*96 fp32

    // 1) LayerNorm -> bf16
    ln_kernel<<<NROWS, 256, 0, stream>>>(x, norm_w, norm_b, xnb);
    // 1b) weight converts
    cvt_kernel<<<(2 * DINNER * DMODEL) / 1024, 256, 0, stream>>>(in_proj_w, wib);
    cvt_kernel<<<(DMODEL * DINNER) / 1024, 256, 0, stream>>>(out_proj_w, wob);
    cvt_kernel<<<(DINNER * DTRANK) / 1024, 256, 0, stream>>>(dt_proj_w, wdt);
    // 2) in_proj (bf16 MFMA): n<2048 -> xc16, n>=2048 -> zb (both bf16)
    gemm_bf16<0><<<dim3((2 * DINNER) / 128, NROWS / 128), 256, 0, stream>>>(
        xnb, DMODEL, wib, DMODEL, xc16, zb, DINNER, DINNER, DMODEL, nullptr);
    // 3) conv + SiLU (bf16 in/out) -> u16
    conv_silu_kernel<<<NROWS, 256, 0, stream>>>(xc16, conv_w, conv_b, u16);
    // 4) x_proj split-K (bf16 A) -> xdbl (fp32 + bf16)
    xp_partial<<<dim3(2, NROWS / 64, KS), 256, 0, stream>>>(u16, x_proj_w, xpp);
    xp_reduce<<<(NROWS * 96) / 256, 256, 0, stream>>>(xpp, xdbl, xdbl16);
    // 5) dt_proj + softplus (bf16 MFMA, K=64) -> dt16
    gemm_bf16<1><<<dim3(DINNER / 128, NROWS / 128), 256, 0, stream>>>(
        (const __hip_bfloat16*)xdbl16, 96, wdt, DTRANK,
        dt16, nullptr, 1 << 30, DINNER, DTRANK, dt_proj_b);
    // 6) chunked selective scan (s-parallel) -> ybb (bf16)
    scan_pass1<<<BB * NC * (DINNER / 16), 256, 0, stream>>>(
        dt16, u16, xdbl, A_log, hloc, aprod);
    scan_pass2<<<(BB * DINNER * DSTATE) / 256, 256, 0, stream>>>(hloc, aprod);
    scan_pass3<<<BB * NC * (DINNER / 16), 256, 0, stream>>>(
        dt16, u16, xdbl, zb, A_log, Dp, hloc, ybb);
    // 7) out_proj + residual (bf16 MFMA)
    gemm_bf16<2><<<dim3(DMODEL / 128, NROWS / 128), 256, 0, stream>>>(
        ybb, DINNER, wob, DINNER, out, nullptr, 1 << 30, DMODEL, DINNER, x);
}

// Round 9
// 411.044 us; speedup vs baseline: 1.4347x; 1.4347x over previous
//
#include <hip/hip_runtime.h>
#include <hip/hip_bf16.h>
#include <math.h>

#define BB 2
#define LL 2048
#define DMODEL 1024
#define DINNER 2048
#define DSTATE 16
#define DTRANK 64
#define NROWS (BB * LL)   // 4096
#define NC 64             // number of time chunks
#define CK 32             // chunk length (NC*CK == LL)
#define KS 16             // split-K factor for x_proj
#define KCH (DINNER / KS) // 128

typedef __bf16 bf16x8 __attribute__((ext_vector_type(8)));
typedef float  f32x4  __attribute__((ext_vector_type(4)));
typedef ushort us8    __attribute__((ext_vector_type(8)));
typedef __attribute__((address_space(3))) void       as3_void;
typedef const __attribute__((address_space(1))) void as1_cvoid;

__device__ __forceinline__ ushort f2bf(float x) {
    __hip_bfloat16 h = __float2bfloat16(x);
    return *(ushort*)&h;
}
__device__ __forceinline__ float bf2f(ushort u) {
    unsigned int v = ((unsigned int)u) << 16;
    return *(float*)&v;
}

// ---------------- LayerNorm -> bf16 output ----------------------------------
__global__ __launch_bounds__(256) void ln_kernel(const float* __restrict__ x,
                                                 const float* __restrict__ w,
                                                 const float* __restrict__ b,
                                                 __hip_bfloat16* __restrict__ xn) {
    int row = blockIdx.x;
    const float* xr = x + (size_t)row * DMODEL;
    float4 v = reinterpret_cast<const float4*>(xr)[threadIdx.x];
    float s  = v.x + v.y + v.z + v.w;
    float ss = v.x * v.x + v.y * v.y + v.z * v.z + v.w * v.w;
    for (int off = 32; off > 0; off >>= 1) {
        s  += __shfl_down(s, off);
        ss += __shfl_down(ss, off);
    }
    __shared__ float red0[4], red1[4];
    __shared__ float mu_s, rstd_s;
    int lane = threadIdx.x & 63, wv = threadIdx.x >> 6;
    if (lane == 0) { red0[wv] = s; red1[wv] = ss; }
    __syncthreads();
    if (threadIdx.x == 0) {
        float S = red0[0] + red0[1] + red0[2] + red0[3];
        float SS = red1[0] + red1[1] + red1[2] + red1[3];
        float mu = S * (1.0f / DMODEL);
        float var = SS * (1.0f / DMODEL) - mu * mu;
        mu_s = mu;
        rstd_s = rsqrtf(var + 1e-5f);
    }
    __syncthreads();
    float mu = mu_s, rstd = rstd_s;
    float4 wv4 = reinterpret_cast<const float4*>(w)[threadIdx.x];
    float4 bv4 = reinterpret_cast<const float4*>(b)[threadIdx.x];
    ushort4 o;
    o.x = f2bf((v.x - mu) * rstd * wv4.x + bv4.x);
    o.y = f2bf((v.y - mu) * rstd * wv4.y + bv4.y);
    o.z = f2bf((v.z - mu) * rstd * wv4.z + bv4.z);
    o.w = f2bf((v.w - mu) * rstd * wv4.w + bv4.w);
    *reinterpret_cast<ushort4*>((ushort*)xn + (size_t)row * DMODEL + threadIdx.x * 4) = o;
}

// ---------------- f32 -> bf16 convert (weights) ------------------------------
__global__ __launch_bounds__(256) void cvt_kernel(const float* __restrict__ in,
                                                  __hip_bfloat16* __restrict__ o) {
    int i = (blockIdx.x * 256 + threadIdx.x) * 4;
    float4 v = *reinterpret_cast<const float4*>(in + i);
    ushort4 p;
    p.x = f2bf(v.x); p.y = f2bf(v.y); p.z = f2bf(v.z); p.w = f2bf(v.w);
    *reinterpret_cast<ushort4*>((ushort*)o + i) = p;
}

// ---------------- bf16 MFMA GEMM: C[M,N] = A[M,K] @ W[N,K]^T  ----------------
// EPI 0: bf16 stores, split: n < nsplit -> C; n >= nsplit -> C2 (both ushort*)
// EPI 1: softplus(acc + R[n]) -> bf16 store to C   (R = bias)
// EPI 2: fp32 store with residual: C[m*ldc+n] = acc + R[m*ldc+n]
template <int EPI>
__global__ __launch_bounds__(256) void gemm_bf16(
    const __hip_bfloat16* __restrict__ A, int lda,
    const __hip_bfloat16* __restrict__ W, int ldw,
    void* __restrict__ C, void* __restrict__ C2, int nsplit, int ldc,
    int K, const float* __restrict__ R) {
    __shared__ ushort As[128][32];
    __shared__ ushort Bs[128][32];
    int tid = threadIdx.x;
    int w = tid >> 6, lane = tid & 63;
    int m0 = blockIdx.y * 128, n0 = blockIdx.x * 128;
    int wr = w >> 1, wc = w & 1;

    int srow = (w << 4) + (lane >> 2);
    int skoff = (lane & 3) << 3;
    const ushort* gA = (const ushort*)A + (size_t)(m0 + srow) * lda + skoff;
    const ushort* gB = (const ushort*)W + (size_t)(n0 + srow) * ldw + skoff;
    char* ldsA0 = (char*)&As[0][0] + w * 1024;
    char* ldsB0 = (char*)&Bs[0][0] + w * 1024;

    f32x4 acc[4][4] = {};
    int frow = (lane & 15);
    int fk   = (lane >> 4) << 3;

    for (int k0 = 0; k0 < K; k0 += 32) {
        __syncthreads();
        __builtin_amdgcn_global_load_lds((as1_cvoid*)(gA + k0),                    (as3_void*)(ldsA0),        16, 0, 0);
        __builtin_amdgcn_global_load_lds((as1_cvoid*)(gA + (size_t)64 * lda + k0), (as3_void*)(ldsA0 + 4096), 16, 0, 0);
        __builtin_amdgcn_global_load_lds((as1_cvoid*)(gB + k0),                    (as3_void*)(ldsB0),        16, 0, 0);
        __builtin_amdgcn_global_load_lds((as1_cvoid*)(gB + (size_t)64 * ldw + k0), (as3_void*)(ldsB0 + 4096), 16, 0, 0);
        __syncthreads();

        bf16x8 af[4], bfr[4];
#pragma unroll
        for (int mi = 0; mi < 4; mi++)
            af[mi] = *(const bf16x8*)&As[wr * 64 + mi * 16 + frow][fk];
#pragma unroll
        for (int ni = 0; ni < 4; ni++)
            bfr[ni] = *(const bf16x8*)&Bs[wc * 64 + ni * 16 + frow][fk];
#pragma unroll
        for (int mi = 0; mi < 4; mi++)
#pragma unroll
            for (int ni = 0; ni < 4; ni++)
                acc[mi][ni] = __builtin_amdgcn_mfma_f32_16x16x32_bf16(
                    af[mi], bfr[ni], acc[mi][ni], 0, 0, 0);
    }

    int crow = (lane >> 4) << 2;
    int ccol = lane & 15;
    bool toz = (EPI == 0) && (n0 >= nsplit);
    int nbase = toz ? (n0 - nsplit) : n0;
    ushort* Cu = toz ? (ushort*)C2 : (ushort*)C;
#pragma unroll
    for (int mi = 0; mi < 4; mi++) {
#pragma unroll
        for (int ni = 0; ni < 4; ni++) {
#pragma unroll
            for (int r = 0; r < 4; r++) {
                int m = m0 + wr * 64 + mi * 16 + crow + r;
                int n = nbase + wc * 64 + ni * 16 + ccol;
                float v = acc[mi][ni][r];
                if (EPI == 2) {
                    v += R[(size_t)m * ldc + n];
                    ((float*)C)[(size_t)m * ldc + n] = v;
                } else if (EPI == 1) {
                    v += R[n];
                    v = (v > 20.f) ? v : log1pf(__expf(v));
                    ((ushort*)C)[(size_t)m * ldc + n] = f2bf(v);
                } else {
                    Cu[(size_t)m * ldc + n] = f2bf(v);
                }
            }
        }
    }
}

// ---------------- x_proj split-K (bf16 A): partial + reduce ------------------
__global__ __launch_bounds__(256) void xp_partial(
    const ushort* __restrict__ A,  // u16 [4096][2048] bf16
    const float* __restrict__ W,   // x_proj_w [96][2048]
    float* __restrict__ P) {       // [KS][4096][96]
    __shared__ float As[16][64];
    __shared__ float Ws[16][64];
    int m0 = blockIdx.y * 64;
    int n0 = blockIdx.x * 64;
    int kbase = blockIdx.z * KCH;
    int tid = threadIdx.x;
    int tm = tid >> 4, tn = tid & 15;
    int lr = tid >> 2;
    int lk = (tid & 3) << 2;

    float acc[4][4] = {};

    for (int k0 = kbase; k0 < kbase + KCH; k0 += 16) {
        ushort4 au = *reinterpret_cast<const ushort4*>(A + (size_t)(m0 + lr) * DINNER + k0 + lk);
        float4 av = make_float4(bf2f(au.x), bf2f(au.y), bf2f(au.z), bf2f(au.w));
        float4 wvv;
        int wn = n0 + lr;
        if (wn < 96)
            wvv = *reinterpret_cast<const float4*>(W + (size_t)wn * DINNER + k0 + lk);
        else
            wvv = make_float4(0.f, 0.f, 0.f, 0.f);
        __syncthreads();
        As[lk + 0][lr] = av.x; As[lk + 1][lr] = av.y;
        As[lk + 2][lr] = av.z; As[lk + 3][lr] = av.w;
        Ws[lk + 0][lr] = wvv.x; Ws[lk + 1][lr] = wvv.y;
        Ws[lk + 2][lr] = wvv.z; Ws[lk + 3][lr] = wvv.w;
        __syncthreads();
#pragma unroll
        for (int k = 0; k < 16; k++) {
            float4 a = *reinterpret_cast<const float4*>(&As[k][tm << 2]);
            float4 bv = *reinterpret_cast<const float4*>(&Ws[k][tn << 2]);
            float ar[4] = {a.x, a.y, a.z, a.w};
            float br[4] = {bv.x, bv.y, bv.z, bv.w};
#pragma unroll
            for (int i = 0; i < 4; i++)
#pragma unroll
                for (int j = 0; j < 4; j++)
                    acc[i][j] = fmaf(ar[i], br[j], acc[i][j]);
        }
    }
    float* Pz = P + (size_t)blockIdx.z * NROWS * 96;
#pragma unroll
    for (int i = 0; i < 4; i++) {
        int m = m0 + (tm << 2) + i;
#pragma unroll
        for (int j = 0; j < 4; j++) {
            int n = n0 + (tn << 2) + j;
            if (n < 96)
                Pz[(size_t)m * 96 + n] = acc[i][j];
        }
    }
}

// reduce partials -> xdbl fp32 (scan B/C) + xdbl bf16 (dt MFMA input)
__global__ __launch_bounds__(256) void xp_reduce(
    const float* __restrict__ P, float* __restrict__ xdbl,
    ushort* __restrict__ xdbl16) {
    int i = blockIdx.x * 256 + threadIdx.x;
    float s = 0.f;
#pragma unroll
    for (int z = 0; z < KS; z++)
        s += P[(size_t)z * NROWS * 96 + i];
    xdbl[i] = s;
    xdbl16[i] = f2bf(s);
}

// ------ causal depthwise conv (width 4) + SiLU; bf16 in/out, 8 ch/thread -----
__global__ __launch_bounds__(256) void conv_silu_kernel(
    const ushort* __restrict__ xc16, const float* __restrict__ cw,
    const float* __restrict__ cb, ushort* __restrict__ u16) {
    int r = blockIdx.x;
    int l = r & (LL - 1);
    int c0 = threadIdx.x << 3;            // 8 channels per thread
    const ushort* base = xc16 + (size_t)r * DINNER + c0;
    us8 z8 = {0, 0, 0, 0, 0, 0, 0, 0};
    us8 v0 = *(const us8*)(base);
    us8 v1 = (l >= 1) ? *(const us8*)(base - DINNER)     : z8;
    us8 v2 = (l >= 2) ? *(const us8*)(base - 2 * DINNER) : z8;
    us8 v3 = (l >= 3) ? *(const us8*)(base - 3 * DINNER) : z8;
    us8 o;
#pragma unroll
    for (int j = 0; j < 8; j++) {
        float4 wj = reinterpret_cast<const float4*>(cw)[c0 + j];
        float acc = cb[c0 + j];
        acc = fmaf(bf2f(v3[j]), wj.x, acc);
        acc = fmaf(bf2f(v2[j]), wj.y, acc);
        acc = fmaf(bf2f(v1[j]), wj.z, acc);
        acc = fmaf(bf2f(v0[j]), wj.w, acc);
        float sig = 1.f / (1.f + __expf(-acc));
        o[j] = f2bf(acc * sig);
    }
    *(us8*)(u16 + (size_t)r * DINNER + c0) = o;
}

// --------- chunked selective scan, d-parallel (1 thread = 1 channel) ---------
// hloc/aprod layout: [bc][s][d]  (d fastest -> coalesced)
__global__ __launch_bounds__(256) void scan_pass1(
    const ushort* __restrict__ dt16, const ushort* __restrict__ u16,
    const float* __restrict__ xdbl, const float* __restrict__ A_log,
    float* __restrict__ hloc, float* __restrict__ aprod) {
    int bc = blockIdx.x >> 3;              // b*NC + c
    int b = bc >> 6, c = bc & (NC - 1);
    int d = ((blockIdx.x & 7) << 8) + threadIdx.x;
    float a2[DSTATE];
#pragma unroll
    for (int s = 0; s < DSTATE; s++)
        a2[s] = -__expf(A_log[d * DSTATE + s]) * 1.44269504089f;
    float h[DSTATE], ap[DSTATE];
#pragma unroll
    for (int s = 0; s < DSTATE; s++) { h[s] = 0.f; ap[s] = 1.f; }

    int t0 = c * CK;
    const ushort* dtp = dt16 + ((size_t)b * LL + t0) * DINNER + d;
    const ushort* up  = u16  + ((size_t)b * LL + t0) * DINNER + d;
    const float* xr0  = xdbl + ((size_t)b * LL + t0) * 96;

    for (int t = 0; t < CK; t++) {
        float dtv = bf2f(dtp[(size_t)t * DINNER]);
        float uv  = bf2f(up[(size_t)t * DINNER]);
        float du  = dtv * uv;
        const float* xr = xr0 + t * 96;    // uniform -> scalar loads
#pragma unroll
        for (int s = 0; s < DSTATE; s++) {
            float dA = exp2f(dtv * a2[s]);
            h[s] = fmaf(dA, h[s], du * xr[64 + s]);
            ap[s] *= dA;
        }
    }
    size_t base = ((size_t)bc * DSTATE) * DINNER + d;
#pragma unroll
    for (int s = 0; s < DSTATE; s++) {
        hloc[base + (size_t)s * DINNER]  = h[s];
        aprod[base + (size_t)s * DINNER] = ap[s];
    }
}

__global__ __launch_bounds__(256) void scan_pass2(
    float* __restrict__ hloc, const float* __restrict__ aprod) {
    int idx = blockIdx.x * 256 + threadIdx.x;
    int d = idx & (DINNER - 1);
    int s = (idx >> 11) & (DSTATE - 1);
    int b = idx >> 15;
    float run = 0.f;
    for (int c = 0; c < NC; c++) {
        size_t off = ((size_t)((b * NC + c) * DSTATE + s)) * DINNER + d;
        float hl = hloc[off];
        float ap = aprod[off];
        hloc[off] = run;
        run = fmaf(ap, run, hl);
    }
}

__global__ __launch_bounds__(256) void scan_pass3(
    const ushort* __restrict__ dt16, const ushort* __restrict__ u16,
    const float* __restrict__ xdbl, const ushort* __restrict__ zb,
    const float* __restrict__ A_log, const float* __restrict__ Dp,
    const float* __restrict__ hinit, __hip_bfloat16* __restrict__ y) {
    int bc = blockIdx.x >> 3;
    int b = bc >> 6, c = bc & (NC - 1);
    int d = ((blockIdx.x & 7) << 8) + threadIdx.x;
    float a2[DSTATE];
#pragma unroll
    for (int s = 0; s < DSTATE; s++)
        a2[s] = -__expf(A_log[d * DSTATE + s]) * 1.44269504089f;
    float Dd = Dp[d];
    float h[DSTATE];
    size_t base = ((size_t)bc * DSTATE) * DINNER + d;
#pragma unroll
    for (int s = 0; s < DSTATE; s++) h[s] = hinit[base + (size_t)s * DINNER];

    int t0 = c * CK;
    const ushort* dtp = dt16 + ((size_t)b * LL + t0) * DINNER + d;
    const ushort* up  = u16  + ((size_t)b * LL + t0) * DINNER + d;
    const ushort* zp  = zb   + ((size_t)b * LL + t0) * DINNER + d;
    const float* xr0  = xdbl + ((size_t)b * LL + t0) * 96;
    ushort* yp = (ushort*)y + ((size_t)b * LL + t0) * DINNER + d;

    for (int t = 0; t < CK; t++) {
        float dtv = bf2f(dtp[(size_t)t * DINNER]);
        float uv  = bf2f(up[(size_t)t * DINNER]);
        float du  = dtv * uv;
        const float* xr = xr0 + t * 96;
        float yv = 0.f;
#pragma unroll
        for (int s = 0; s < DSTATE; s++) {
            float dA = exp2f(dtv * a2[s]);
            h[s] = fmaf(dA, h[s], du * xr[64 + s]);
            yv = fmaf(h[s], xr[80 + s], yv);
        }
        float zv = bf2f(zp[(size_t)t * DINNER]);
        float sig = 1.f / (1.f + __expf(-zv));
        yv = (yv + uv * Dd) * (zv * sig);
        yp[(size_t)t * DINNER] = f2bf(yv);
    }
}

// ---------------------------------------------------------------------------
extern "C" void kernel_launch(void* const* d_in, const int* in_sizes, int n_in,
                              void* d_out, int out_size, void* d_ws, size_t ws_size,
                              hipStream_t stream) {
    const float* x         = (const float*)d_in[0];
    const float* norm_w    = (const float*)d_in[1];
    const float* norm_b    = (const float*)d_in[2];
    const float* in_proj_w = (const float*)d_in[3];
    const float* conv_w    = (const float*)d_in[4];
    const float* conv_b    = (const float*)d_in[5];
    const float* x_proj_w  = (const float*)d_in[6];
    const float* dt_proj_w = (const float*)d_in[7];
    const float* dt_proj_b = (const float*)d_in[8];
    const float* A_log     = (const float*)d_in[9];
    const float* Dp        = (const float*)d_in[10];
    const float* out_proj_w= (const float*)d_in[11];
    float* out = (float*)d_out;

    float* ws   = (float*)d_ws;
    const size_t NI = (size_t)NROWS * DINNER;          // 8,388,608 elements
    ushort* xc16  = (ushort*)ws;                       // NI bf16
    ushort* zb    = (ushort*)(ws + NI / 2);            // NI bf16
    ushort* u16   = (ushort*)(ws + NI);                // NI bf16
    ushort* dt16  = (ushort*)(ws + NI + NI / 2);       // NI bf16
    float*  xdbl  = ws + 2 * NI;                       // NROWS*96 fp32
    ushort* xdbl16 = (ushort*)(xdbl + (size_t)NROWS * 96);   // NROWS*96 bf16
    float*  nxt   = xdbl + (size_t)NROWS * 96 + (size_t)NROWS * 96 / 2;
    __hip_bfloat16* xnb = (__hip_bfloat16*)nxt;        // NROWS*DMODEL bf16
    __hip_bfloat16* ybb = xnb + (size_t)NROWS * DMODEL;
    __hip_bfloat16* wib = ybb + NI;                    // in_proj_w bf16
    __hip_bfloat16* wob = wib + (size_t)2 * DINNER * DMODEL;
    __hip_bfloat16* wdt = wob + (size_t)DMODEL * DINNER;     // dt_proj_w bf16
    float* hloc  = (float*)(wdt + (size_t)DINNER * DTRANK);  // NI/2 fp32
    float* aprod = hloc + NI / 2;                            // NI/2 fp32
    float* xpp   = aprod + NI / 2;                           // KS*NROWS*96 fp32

    // 1) LayerNorm -> bf16
    ln_kernel<<<NROWS, 256, 0, stream>>>(x, norm_w, norm_b, xnb);
    // 1b) weight converts
    cvt_kernel<<<(2 * DINNER * DMODEL) / 1024, 256, 0, stream>>>(in_proj_w, wib);
    cvt_kernel<<<(DMODEL * DINNER) / 1024, 256, 0, stream>>>(out_proj_w, wob);
    cvt_kernel<<<(DINNER * DTRANK) / 1024, 256, 0, stream>>>(dt_proj_w, wdt);
    // 2) in_proj (bf16 MFMA): n<2048 -> xc16, n>=2048 -> zb (both bf16)
    gemm_bf16<0><<<dim3((2 * DINNER) / 128, NROWS / 128), 256, 0, stream>>>(
        xnb, DMODEL, wib, DMODEL, xc16, zb, DINNER, DINNER, DMODEL, nullptr);
    // 3) conv + SiLU (bf16 in/out) -> u16
    conv_silu_kernel<<<NROWS, 256, 0, stream>>>(xc16, conv_w, conv_b, u16);
    // 4) x_proj split-K (bf16 A) -> xdbl (fp32 + bf16)
    xp_partial<<<dim3(2, NROWS / 64, KS), 256, 0, stream>>>(u16, x_proj_w, xpp);
    xp_reduce<<<(NROWS * 96) / 256, 256, 0, stream>>>(xpp, xdbl, xdbl16);
    // 5) dt_proj + softplus (bf16 MFMA, K=64) -> dt16
    gemm_bf16<1><<<dim3(DINNER / 128, NROWS / 128), 256, 0, stream>>>(
        (const __hip_bfloat16*)xdbl16, 96, wdt, DTRANK,
        dt16, nullptr, 1 << 30, DINNER, DTRANK, dt_proj_b);
    // 6) chunked selective scan (d-parallel) -> ybb (bf16)
    scan_pass1<<<BB * NC * (DINNER / 256), 256, 0, stream>>>(
        dt16, u16, xdbl, A_log, hloc, aprod);
    scan_pass2<<<(BB * DSTATE * DINNER) / 256, 256, 0, stream>>>(hloc, aprod);
    scan_pass3<<<BB * NC * (DINNER / 256), 256, 0, stream>>>(
        dt16, u16, xdbl, zb, A_log, Dp, hloc, ybb);
    // 7) out_proj + residual (bf16 MFMA)
    gemm_bf16<2><<<dim3(DMODEL / 128, NROWS / 128), 256, 0, stream>>>(
        ybb, DINNER, wob, DINNER, out, nullptr, 1 << 30, DMODEL, DINNER, x);
}